// Round 4
// baseline (630.868 us; speedup 1.0000x reference)
//
#include <hip/hip_runtime.h>
#include <hip/hip_bf16.h>
#include <stdint.h>

// MPO linear: out = x @ W^T + bias, W[m1*64+m2, n1*64+n2] = sum_r c1[m1,n1,r] c2[r,m2,n2]
// R4: (a) unique kernel names so rocprof localizes the 205us prologue gap;
//     (b) main GEMM switched to v_mfma_f32_32x32x16_bf16 (4096 FLOP/cyc vs 3378 for
//         16x16x32; same LDS traffic, same barrier structure). W-GEMM unchanged (16x16).
//     Note: SQ_LDS_BANK_CONFLICT==2^25 exactly in R1+R3 => 4cyc/ds_read_b128 inherent
//     phase accounting, NOT addressable conflicts; swizzle kept (free, proven correct).

#define TOKENS 8192
#define DIN    4096
#define DOUT   4096
#define RANK   256

typedef __attribute__((ext_vector_type(8)))  short  short8;
typedef __attribute__((ext_vector_type(4)))  float  floatx4;
typedef __attribute__((ext_vector_type(16))) float  floatx16;

__device__ __forceinline__ unsigned short f2bf(float f) {
  union { float f; unsigned u; } v; v.f = f;
  unsigned r = v.u + 0x7FFFu + ((v.u >> 16) & 1u);  // round-to-nearest-even
  return (unsigned short)(r >> 16);
}

__device__ __forceinline__ void gl2lds16(const void* g, void* l) {
  __builtin_amdgcn_global_load_lds(
      (const __attribute__((address_space(1))) unsigned int*)g,
      (__attribute__((address_space(3))) unsigned int*)l,
      16, 0, 0);
}

// ---- fp32 -> bf16 convert of x, n multiple of 2048 ----
__global__ __launch_bounds__(256) void k_conv_x(const float* __restrict__ src,
                                                unsigned short* __restrict__ dst,
                                                int n) {
  int i = (blockIdx.x * 256 + threadIdx.x) * 8;
  if (i >= n) return;
  float4 a = *(const float4*)(src + i);
  float4 b = *(const float4*)(src + i + 4);
  short8 o;
  o[0] = (short)f2bf(a.x); o[1] = (short)f2bf(a.y);
  o[2] = (short)f2bf(a.z); o[3] = (short)f2bf(a.w);
  o[4] = (short)f2bf(b.x); o[5] = (short)f2bf(b.y);
  o[6] = (short)f2bf(b.z); o[7] = (short)f2bf(b.w);
  *(short8*)(dst + i) = o;
}

// identical body, distinct name for rocprof attribution
__global__ __launch_bounds__(256) void k_conv_c1(const float* __restrict__ src,
                                                 unsigned short* __restrict__ dst,
                                                 int n) {
  int i = (blockIdx.x * 256 + threadIdx.x) * 8;
  if (i >= n) return;
  float4 a = *(const float4*)(src + i);
  float4 b = *(const float4*)(src + i + 4);
  short8 o;
  o[0] = (short)f2bf(a.x); o[1] = (short)f2bf(a.y);
  o[2] = (short)f2bf(a.z); o[3] = (short)f2bf(a.w);
  o[4] = (short)f2bf(b.x); o[5] = (short)f2bf(b.y);
  o[6] = (short)f2bf(b.z); o[7] = (short)f2bf(b.w);
  *(short8*)(dst + i) = o;
}

// ---- core2 [256][4096] f32  ->  c2t [4096][256] bf16 (LDS tile transpose) ----
__global__ __launch_bounds__(256) void k_tr_c2(const float* __restrict__ c2,
                                               unsigned short* __restrict__ c2t) {
  __shared__ float tile[64][65];
  const int p0 = blockIdx.x * 64;
  const int r0 = blockIdx.y * 64;
  {
    const int px = threadIdx.x & 63;
    const int rb = threadIdx.x >> 6;           // 0..3
    for (int s = 0; s < 16; ++s) {
      int r = rb + s * 4;
      tile[r][px] = c2[(size_t)(r0 + r) * 4096 + p0 + px];
    }
  }
  __syncthreads();
  {
    const int rx = threadIdx.x & 63;
    const int pb = threadIdx.x >> 6;
    for (int s = 0; s < 16; ++s) {
      int p = pb + s * 4;
      c2t[(size_t)(p0 + p) * 256 + r0 + rx] = f2bf(tile[rx][p]);
    }
  }
}

// ---- W-GEMM (16x16x32 path, R1/R3-proven): W = c1b @ c2t^T, permuted bf16 store ----
__global__ __launch_bounds__(256) void k_gemm_w(const unsigned short* __restrict__ A,
                                                const unsigned short* __restrict__ B,
                                                unsigned short* __restrict__ outW) {
  constexpr int K = RANK, BK = 32, CM = 3;
  __shared__ __align__(16) unsigned short As[128 * BK];
  __shared__ __align__(16) unsigned short Bs[128 * BK];

  const int tid  = threadIdx.x;
  const int lane = tid & 63;
  const int wave = tid >> 6;
  const int m0 = blockIdx.y * 128;
  const int n0 = blockIdx.x * 128;
  const int waveM = (wave & 1) * 64;
  const int waveN = (wave >> 1) * 64;
  const int l15  = lane & 15;
  const int quad = lane >> 4;

  floatx4 acc[4][4];
#pragma unroll
  for (int i = 0; i < 4; ++i)
#pragma unroll
    for (int j = 0; j < 4; ++j) acc[i][j] = (floatx4)0.0f;

  const size_t rowBytes = (size_t)K * 2;

  for (int kt = 0; kt < K; kt += BK) {
    __syncthreads();
#pragma unroll
    for (int j = 0; j < 2; ++j) {
      const int flat = (j * 4 + wave) * 1024 + lane * 16;
      const int row  = flat / 64;
      const int cs   = ((flat >> 4) & CM) ^ (row & CM);
      const int ldsb = (j * 4 + wave) * 1024;
      gl2lds16((const char*)A + (size_t)(m0 + row) * rowBytes + (size_t)kt * 2 + cs * 16,
               (char*)As + ldsb);
      gl2lds16((const char*)B + (size_t)(n0 + row) * rowBytes + (size_t)kt * 2 + cs * 16,
               (char*)Bs + ldsb);
    }
    __syncthreads();

    short8 af[4], bf[4];
#pragma unroll
    for (int mi = 0; mi < 4; ++mi) {
      const int row = waveM + mi * 16 + l15;
      const int cs  = quad ^ (row & CM);
      af[mi] = *(const short8*)(As + row * BK + cs * 8);
    }
#pragma unroll
    for (int ni = 0; ni < 4; ++ni) {
      const int row = waveN + ni * 16 + l15;
      const int cs  = quad ^ (row & CM);
      bf[ni] = *(const short8*)(Bs + row * BK + cs * 8);
    }
#pragma unroll
    for (int mi = 0; mi < 4; ++mi)
#pragma unroll
      for (int ni = 0; ni < 4; ++ni)
        acc[mi][ni] = __builtin_amdgcn_mfma_f32_16x16x32_bf16(af[mi], bf[ni], acc[mi][ni], 0, 0, 0);
  }

  // permuted store: arow=(m1,n1), bcol=(m2,n2) -> W[(m1*64+m2)][(n1*64+n2)]
#pragma unroll
  for (int ni = 0; ni < 4; ++ni) {
    const int bcol = n0 + waveN + ni * 16 + l15;
    const int m2 = bcol >> 6, n2 = bcol & 63;
#pragma unroll
    for (int mi = 0; mi < 4; ++mi) {
      const int arow0 = m0 + waveM + mi * 16 + quad * 4;
#pragma unroll
      for (int r = 0; r < 4; ++r) {
        const int arow = arow0 + r;
        const int m1 = arow >> 6, n1 = arow & 63;
        outW[(size_t)(m1 * 64 + m2) * 4096 + (n1 * 64 + n2)] = f2bf(acc[mi][ni][r]);
      }
    }
  }
}

// ---- main GEMM: out = xb @ Wb^T + bias, 32x32x16 MFMA, 128x128 tile, BK=32 ----
// A-frag: m=lane&31, k=(lane>>5)*8+j.  C/D (m74/m101): col=lane&31,
// row=(reg&3)+8*(reg>>2)+4*(lane>>5).
__global__ __launch_bounds__(256) void k_gemm_main(const unsigned short* __restrict__ A,
                                                   const unsigned short* __restrict__ B,
                                                   float* __restrict__ outF,
                                                   const float* __restrict__ bias) {
  constexpr int K = DIN, BK = 32, CM = 3;
  __shared__ __align__(16) unsigned short As[128 * BK];
  __shared__ __align__(16) unsigned short Bs[128 * BK];

  const int tid  = threadIdx.x;
  const int lane = tid & 63;
  const int wave = tid >> 6;
  const int m0 = blockIdx.y * 128;
  const int n0 = blockIdx.x * 128;
  const int waveM = (wave & 1) * 64;
  const int waveN = (wave >> 1) * 64;
  const int l31  = lane & 31;
  const int half = lane >> 5;

  floatx16 acc[2][2];
#pragma unroll
  for (int i = 0; i < 2; ++i)
#pragma unroll
    for (int j = 0; j < 2; ++j) acc[i][j] = (floatx16)0.0f;

  const size_t rowBytes = (size_t)K * 2;

  for (int kt = 0; kt < K; kt += BK) {
    __syncthreads();  // prior K-step's LDS reads done
#pragma unroll
    for (int j = 0; j < 2; ++j) {
      const int flat = (j * 4 + wave) * 1024 + lane * 16;
      const int row  = flat / 64;
      const int cs   = ((flat >> 4) & CM) ^ (row & CM);
      const int ldsb = (j * 4 + wave) * 1024;
      gl2lds16((const char*)A + (size_t)(m0 + row) * rowBytes + (size_t)kt * 2 + cs * 16,
               (char*)As + ldsb);
      gl2lds16((const char*)B + (size_t)(n0 + row) * rowBytes + (size_t)kt * 2 + cs * 16,
               (char*)Bs + ldsb);
    }
    __syncthreads();  // drain vmcnt, LDS visible

#pragma unroll
    for (int kk = 0; kk < 2; ++kk) {   // two K=16 steps
      short8 af[2], bf[2];
#pragma unroll
      for (int mi = 0; mi < 2; ++mi) {
        const int row = waveM + mi * 32 + l31;
        const int cs  = (kk * 2 + half) ^ (row & CM);
        af[mi] = *(const short8*)(As + row * BK + cs * 8);
      }
#pragma unroll
      for (int ni = 0; ni < 2; ++ni) {
        const int row = waveN + ni * 32 + l31;
        const int cs  = (kk * 2 + half) ^ (row & CM);
        bf[ni] = *(const short8*)(Bs + row * BK + cs * 8);
      }
#pragma unroll
      for (int mi = 0; mi < 2; ++mi)
#pragma unroll
        for (int ni = 0; ni < 2; ++ni)
          acc[mi][ni] = __builtin_amdgcn_mfma_f32_32x32x16_bf16(af[mi], bf[ni], acc[mi][ni], 0, 0, 0);
    }
  }

  // epilogue: bias add, fp32 store
#pragma unroll
  for (int ni = 0; ni < 2; ++ni) {
    const int col = n0 + waveN + ni * 32 + l31;
    const float bv = bias[col];
#pragma unroll
    for (int mi = 0; mi < 2; ++mi) {
      const int rbase = m0 + waveM + mi * 32 + 4 * half;
#pragma unroll
      for (int reg = 0; reg < 16; ++reg) {
        const int row = rbase + (reg & 3) + 8 * (reg >> 2);
        outF[(size_t)row * DOUT + col] = acc[mi][ni][reg] + bv;
      }
    }
  }
}

extern "C" void kernel_launch(void* const* d_in, const int* in_sizes, int n_in,
                              void* d_out, int out_size, void* d_ws, size_t ws_size,
                              hipStream_t stream) {
  const float* x    = (const float*)d_in[0];
  const float* c1   = (const float*)d_in[1];
  const float* c2   = (const float*)d_in[2];
  const float* bias = (const float*)d_in[3];
  float* out = (float*)d_out;

  // workspace layout (~105 MB total)
  char* ws = (char*)d_ws;
  unsigned short* xb  = (unsigned short*)ws;                               // 67108864 B
  unsigned short* Wb  = (unsigned short*)(ws + 67108864);                  // 33554432 B
  unsigned short* c1b = (unsigned short*)(ws + 67108864 + 33554432);       //  2097152 B
  unsigned short* c2t = (unsigned short*)(ws + 67108864 + 33554432 + 2097152);  // 2097152 B

  k_conv_x <<<(TOKENS * DIN) / 2048, 256, 0, stream>>>(x, xb, TOKENS * DIN);
  k_conv_c1<<<(64 * 64 * RANK) / 2048, 256, 0, stream>>>(c1, c1b, 64 * 64 * RANK);
  k_tr_c2  <<<dim3(64, 4), 256, 0, stream>>>(c2, c2t);

  // t-GEMM: [4096 x 256] @ [4096 x 256]^T -> W bf16 (permuted store)
  k_gemm_w<<<dim3(32, 32), 256, 0, stream>>>(c1b, c2t, Wb);
  // main GEMM: [8192 x 4096] @ [4096 x 4096]^T + bias -> out fp32
  k_gemm_main<<<dim3(DOUT / 128, TOKENS / 128), 256, 0, stream>>>(xb, Wb, out, bias);
}